// Round 10
// baseline (250.310 us; speedup 1.0000x reference)
//
#include <hip/hip_runtime.h>
#include <math.h>

#define NFFT 256
#define NBINS 129
#define HOP 64
#define NFRAMES 65
#define NB 64
#define LX 4096
#define LH 2048
#define LY 1024
#define NCH 64
#define NBR 3
#define NE 8

#define POOLED_BYTES 33024          // 64*129*4
#define CNT_OFF 33024               // 64 uint counters
#define ZERO_BYTES 33280            // pooled + cnt
#define WTF_OFF 33792               // bf16 A-fragment weights
#define WTF_PER 98304               // bf16 elements per branch
#define IW_OFF 623616               // inds/wts

typedef __attribute__((ext_vector_type(8))) short short8;   // 8 bf16
typedef __attribute__((ext_vector_type(4))) float floatx4;

__device__ __forceinline__ unsigned short bf16r(float f) {  // round-nearest-even
    unsigned u = __builtin_bit_cast(unsigned, f);
    u += 0x7FFFu + ((u >> 16) & 1u);
    return (unsigned short)(u >> 16);
}

// ------- STFT (one frame/block) + wTf build + fused last-block gating -------
// grid (65 frames, 64 batch), 128 threads.
__global__ __launch_bounds__(128) void stft_gating_kernel(
    const float* __restrict__ x,
    const float* __restrict__ wb3, const float* __restrict__ wb5,
    const float* __restrict__ wb7, unsigned short* __restrict__ wTf,
    float* __restrict__ pooled, unsigned int* __restrict__ cnt,
    const float* __restrict__ Wg1, const float* __restrict__ bg1,
    const float* __restrict__ Wg2, const float* __restrict__ bg2,
    const float* __restrict__ Wg3, const float* __restrict__ bg3,
    int* __restrict__ inds, float* __restrict__ wts) {
    __shared__ float xw[NFFT];
    __shared__ int islast;
    const int f = blockIdx.x, b = blockIdx.y;
    const int tid = threadIdx.x;

    // build wTf[br][e][mw][i][kb][lane][j] in MFMA A-fragment order:
    //   c2 = mw*16 + (lane&15), cl = kb*32 + (lane>>4)*8 + j
    {
        int bid = b * NFRAMES + f;
        for (int fi = bid * 128 + tid; fi < 3 * WTF_PER;
             fi += NB * NFRAMES * 128) {
            int br = fi / WTF_PER, r = fi % WTF_PER;
            int e = r / 12288;
            int r2 = r % 12288;
            int mw = r2 / 3072;
            int r3 = r2 % 3072;
            int i = r3 / 1024;
            int r4 = r3 % 1024;
            int kb = r4 / 512;
            int r5 = r4 % 512;
            int lane = r5 / 8, j = r5 % 8;
            int c2 = mw * 16 + (lane & 15);
            int cl = kb * 32 + (lane >> 4) * 8 + j;
            const float* src = (br == 0) ? wb3 : (br == 1) ? wb5 : wb7;
            wTf[fi] = bf16r(src[((e * 64 + c2) * 64 + cl) * 3 + i]);
        }
    }

    // stage windowed frame
    for (int n = tid; n < NFFT; n += 128) {
        float a2 = (float)(2.0 * 3.14159265358979323846 / 256.0) * (float)n;
        float sn, cn;
        sincosf(a2, &sn, &cn);
        float win = 0.5f - 0.5f * cn;             // Hann
        int q = f * HOP + n - 128;
        int xi = q < 0 ? -q : (q >= LX ? (2 * LX - 2 - q) : q);  // reflect
        xw[n] = x[b * LX + xi] * win;
    }
    __syncthreads();

    // phasor DFT, bin k = tid; Nyquist folded into the same loop
    const int k = tid;
    float ang = (float)(2.0 * 3.14159265358979323846 / 256.0) * (float)k;
    float s1, c1;
    sincosf(ang, &s1, &c1);
    float c = 1.f, s = 0.f;
    float re = 0.f, im = 0.f, rN = 0.f;
    for (int n = 0; n < NFFT; n += 2) {
        float v0 = xw[n], v1 = xw[n + 1];
        re = fmaf(v0, c, re);
        im = fmaf(v0, s, im);
        rN += v0;
        float t = c * c1 - s * s1;
        s = c * s1 + s * c1;
        c = t;
        re = fmaf(v1, c, re);
        im = fmaf(v1, s, im);
        rN -= v1;
        t = c * c1 - s * s1;
        s = c * s1 + s * c1;
        c = t;
    }
    atomicAdd(&pooled[b * NBINS + k], sqrtf(re * re + im * im));
    if (tid == 0) atomicAdd(&pooled[b * NBINS + 128], fabsf(rN));

    // last finisher for this batch row runs the gating MLP inline
    if (tid == 0) {
        __threadfence();
        unsigned old = atomicAdd(&cnt[b], 1u);
        islast = (old == NFRAMES - 1) ? 1 : 0;
    }
    __syncthreads();
    if (!islast) return;
    __threadfence();

    __shared__ float pl[NBINS];
    __shared__ float h1[256];
    __shared__ float h2[128];
    __shared__ float lg[NE];

    pl[tid] = __hip_atomic_load(&pooled[b * NBINS + tid], __ATOMIC_RELAXED,
                                __HIP_MEMORY_SCOPE_AGENT) *
              (1.0f / (float)NFRAMES);
    if (tid == 0)
        pl[128] = __hip_atomic_load(&pooled[b * NBINS + 128], __ATOMIC_RELAXED,
                                    __HIP_MEMORY_SCOPE_AGENT) *
                  (1.0f / (float)NFRAMES);
    __syncthreads();
    for (int o = tid; o < 256; o += 128) {
        float v = bg1[o];
        for (int kk = 0; kk < NBINS; ++kk) v += pl[kk] * Wg1[kk * 256 + o];
        h1[o] = fmaxf(v, 0.f);
    }
    __syncthreads();
    {
        float v = bg2[tid];
        for (int kk = 0; kk < 256; ++kk) v += h1[kk] * Wg2[kk * 128 + tid];
        h2[tid] = fmaxf(v, 0.f);
    }
    __syncthreads();
    if (tid < NE) {
        float v = bg3[tid];
        for (int kk = 0; kk < 128; ++kk) v += h2[kk] * Wg3[kk * NE + tid];
        lg[tid] = v;
    }
    __syncthreads();
    if (tid == 0) {
        int i0 = 0;
        float v0 = lg[0];
        for (int i = 1; i < NE; ++i)
            if (lg[i] > v0) { v0 = lg[i]; i0 = i; }
        int i1 = -1;
        float v1 = -3.0e38f;
        for (int i = 0; i < NE; ++i) {
            if (i == i0) continue;
            if (lg[i] > v1) { v1 = lg[i]; i1 = i; }
        }
        float e1 = expf(v1 - v0);
        float w0 = 1.f / (1.f + e1);
        inds[b * 2 + 0] = i0;
        inds[b * 2 + 1] = i1;
        wts[b * 2 + 0] = w0;
        wts[b * 2 + 1] = e1 * w0;
    }
}

// ---------------- Expert path: fp32 conv1 -> bf16 MFMA conv2 ----------------
// (unchanged from R9: passed, absmax 2.4e-4, ~45 us)
#define UT 128
#define HPR 68           // shorts per hp row (64 + 4 pad)
#define HROWS 258

template <int KSZ>
__device__ __attribute__((always_inline)) void expert_body(
    const float* __restrict__ x,
    const float* __restrict__ wa, const float* __restrict__ ba,
    const float* __restrict__ bb, const unsigned short* __restrict__ wTfbr,
    const int* __restrict__ inds, const float* __restrict__ wts,
    float* __restrict__ out, int br, short* hp) {
    const int u0 = blockIdx.x * UT;
    const int b = blockIdx.z;
    const int tid = threadIdx.x;
    const int lane = tid & 63;
    const int quad = lane >> 4;
    const int l15 = lane & 15;
    const int wv = __builtin_amdgcn_readfirstlane(tid >> 6);
    const int mw = wv & 3;           // M-tile (c2 block of 16)
    const int nh = wv >> 2;          // N-half (4 N-tiles each)
    const int pad = KSZ >> 1;
    const int t0 = 2 * u0 - 1;
    const int x0 = 2 * t0 - pad;

    const float* xp = x + b * LX;

    float fin[4][4];
#pragma unroll
    for (int q = 0; q < 4; ++q)
#pragma unroll
        for (int r = 0; r < 4; ++r) fin[q][r] = 0.f;

#pragma unroll 1
    for (int slot = 0; slot < 2; ++slot) {
        const int e = __builtin_amdgcn_readfirstlane(inds[b * 2 + slot]);
        const float wj = wts[b * 2 + slot];

        // first-conv weights for this lane's channel (cl = lane)
        float wr[KSZ];
#pragma unroll
        for (int i = 0; i < KSZ; ++i) wr[i] = wa[(e * NCH + lane) * KSZ + i];
        const float bv = ba[e * NCH + lane];

        __syncthreads();   // protect hp from previous slot's phase C readers

        // ---- phase A: h rows tl = 0..257 ----
#pragma unroll 1
        for (int it = 0; it < 9; ++it) {
            int tb = wv + 8 * it;            // wave-uniform t-block (4 rows)
            if (tb > 64) break;
            int base = x0 + 8 * tb;          // wave-uniform x base
            float xr[16];
            if (base >= 0 && base + 15 < LX) {
#pragma unroll
                for (int ii = 0; ii < 16; ++ii) xr[ii] = xp[base + ii];
            } else {
#pragma unroll
                for (int ii = 0; ii < 16; ++ii) {
                    int xi = base + ii;
                    xr[ii] = (xi >= 0 && xi < LX) ? xp[xi] : 0.f;
                }
            }
#pragma unroll
            for (int m = 0; m < 4; ++m) {
                int tl = 4 * tb + m;
                if (tl > 257) continue;
                int t = t0 + tl;
                float s = bv;
#pragma unroll
                for (int i = 0; i < KSZ; ++i) s += wr[i] * xr[2 * m + i];
                float h = (t >= 0 && t < LH) ? fmaxf(s, 0.f) : 0.f;
                hp[tl * HPR + lane] = (short)bf16r(h);
            }
        }
        __syncthreads();

        // ---- phase C: MFMA GEMM ----
        float br4[4];
#pragma unroll
        for (int r = 0; r < 4; ++r)
            br4[r] = bb[e * NCH + mw * 16 + quad * 4 + r];

        short8 af[3][2];
        {
            const unsigned short* wbase =
                wTfbr + e * 12288 + mw * 3072 + lane * 8;
#pragma unroll
            for (int i = 0; i < 3; ++i)
#pragma unroll
                for (int kb = 0; kb < 2; ++kb)
                    af[i][kb] = *(const short8*)&wbase[i * 1024 + kb * 512];
        }

#pragma unroll 1
        for (int q = 0; q < 4; ++q) {
            int nt = nh * 4 + q;
            int nb = nt * 16 + l15;          // local u (B-layout n = lane&15)
            floatx4 acc = {br4[0], br4[1], br4[2], br4[3]};
#pragma unroll
            for (int i = 0; i < 3; ++i) {
                int tl = 2 * nb + i;         // B row
#pragma unroll
                for (int kb = 0; kb < 2; ++kb) {
                    int sb = tl * HPR + kb * 32 + quad * 8;
                    union { short8 v; unsigned long long q2[2]; } B;
                    B.q2[0] = *(const unsigned long long*)&hp[sb];
                    B.q2[1] = *(const unsigned long long*)&hp[sb + 4];
                    acc = __builtin_amdgcn_mfma_f32_16x16x32_bf16(
                        af[i][kb], B.v, acc, 0, 0, 0);
                }
            }
#pragma unroll
            for (int r = 0; r < 4; ++r)
                fin[q][r] += wj * fmaxf(acc[r], 0.f);
        }
    }

#pragma unroll
    for (int q = 0; q < 4; ++q) {
        int u = u0 + (nh * 4 + q) * 16 + l15;
#pragma unroll
        for (int r = 0; r < 4; ++r) {
            int c2 = mw * 16 + quad * 4 + r;
            out[(long)(b * 192 + br * 64 + c2) * LY + u] = fin[q][r];
        }
    }
}

__global__ __launch_bounds__(512, 2) void expert_kernel(
    const float* __restrict__ x,
    const float* __restrict__ wa3, const float* __restrict__ ba3,
    const float* __restrict__ bb3,
    const float* __restrict__ wa5, const float* __restrict__ ba5,
    const float* __restrict__ bb5,
    const float* __restrict__ wa7, const float* __restrict__ ba7,
    const float* __restrict__ bb7,
    const unsigned short* __restrict__ wTf,
    const int* __restrict__ inds, const float* __restrict__ wts,
    float* __restrict__ out) {
    __shared__ short hp[HROWS * HPR];      // 35.1 KB

    const int br = blockIdx.y;
    if (br == 0)
        expert_body<3>(x, wa3, ba3, bb3, wTf, inds, wts, out, 0, hp);
    else if (br == 1)
        expert_body<5>(x, wa5, ba5, bb5, wTf + WTF_PER, inds, wts, out, 1, hp);
    else
        expert_body<7>(x, wa7, ba7, bb7, wTf + 2 * WTF_PER, inds, wts, out, 2, hp);
}

extern "C" void kernel_launch(void* const* d_in, const int* in_sizes, int n_in,
                              void* d_out, int out_size, void* d_ws, size_t ws_size,
                              hipStream_t stream) {
    const float* x   = (const float*)d_in[0];
    const float* Wg1 = (const float*)d_in[1];
    const float* bg1 = (const float*)d_in[2];
    const float* Wg2 = (const float*)d_in[3];
    const float* bg2 = (const float*)d_in[4];
    const float* Wg3 = (const float*)d_in[5];
    const float* bg3 = (const float*)d_in[6];
    const float* wa3 = (const float*)d_in[7];
    const float* ba3 = (const float*)d_in[8];
    const float* wb3 = (const float*)d_in[9];
    const float* bb3 = (const float*)d_in[10];
    const float* wa5 = (const float*)d_in[11];
    const float* ba5 = (const float*)d_in[12];
    const float* wb5 = (const float*)d_in[13];
    const float* bb5 = (const float*)d_in[14];
    const float* wa7 = (const float*)d_in[15];
    const float* ba7 = (const float*)d_in[16];
    const float* wb7 = (const float*)d_in[17];
    const float* bb7 = (const float*)d_in[18];

    float* pooled = (float*)d_ws;
    unsigned int* cnt = (unsigned int*)((char*)d_ws + CNT_OFF);
    unsigned short* wTf = (unsigned short*)((char*)d_ws + WTF_OFF);
    int* inds = (int*)((char*)d_ws + IW_OFF);
    float* wts = (float*)((char*)d_ws + IW_OFF + 512);

    hipMemsetAsync(d_ws, 0, ZERO_BYTES, stream);
    stft_gating_kernel<<<dim3(NFRAMES, NB), 128, 0, stream>>>(
        x, wb3, wb5, wb7, wTf, pooled, cnt,
        Wg1, bg1, Wg2, bg2, Wg3, bg3, inds, wts);
    expert_kernel<<<dim3(LY / UT, NBR, NB), 512, 0, stream>>>(
        x, wa3, ba3, bb3, wa5, ba5, bb5, wa7, ba7, bb7, wTf,
        inds, wts, (float*)d_out);
}

// Round 11
// 179.805 us; speedup vs baseline: 1.3921x; 1.3921x over previous
//
#include <hip/hip_runtime.h>
#include <math.h>

#define NFFT 256
#define NBINS 129
#define HOP 64
#define NFRAMES 65
#define NB 64
#define LX 4096
#define LH 2048
#define LY 1024
#define NCH 64
#define NBR 3
#define NE 8

#define NFG 13                      // frame groups of 5 (atomic partial rows)
#define PART_STRIDE 132
#define PART_ZERO 440320            // memset span covering part[]
#define WTF_OFF 440320              // bf16 A-fragment weights
#define WTF_PER 98304               // bf16 elements per branch
#define IW_OFF 1031168              // inds/wts

typedef __attribute__((ext_vector_type(8))) short short8;   // 8 bf16
typedef __attribute__((ext_vector_type(4))) float floatx4;

__device__ __forceinline__ unsigned short bf16r(float f) {  // round-nearest-even
    unsigned u = __builtin_bit_cast(unsigned, f);
    u += 0x7FFFu + ((u >> 16) & 1u);
    return (unsigned short)(u >> 16);
}

// ---------------- STFT: one frame/block, 4-way split phasor DFT ------------
// grid (65 frames, 64 batch), 128 threads. Chunk j of 64 samples starts at
// phase k*j*pi/2 whose (cos,sin) is in {0,+-1} -> recombine with sign selects;
// 4 independent 64-step chains hide FMA latency.
__global__ __launch_bounds__(128) void stft_kernel(
    const float* __restrict__ x,
    const float* __restrict__ wb3, const float* __restrict__ wb5,
    const float* __restrict__ wb7, unsigned short* __restrict__ wTf,
    float* __restrict__ part) {
    __shared__ float xw[NFFT];
    const int f = blockIdx.x, b = blockIdx.y;
    const int tid = threadIdx.x;

    // build wTf[br][e][mw][i][kb][lane][j] in MFMA A-fragment order
    {
        int bid = b * NFRAMES + f;
        for (int fi = bid * 128 + tid; fi < 3 * WTF_PER;
             fi += NB * NFRAMES * 128) {
            int br = fi / WTF_PER, r = fi % WTF_PER;
            int e = r / 12288;
            int r2 = r % 12288;
            int mw = r2 / 3072;
            int r3 = r2 % 3072;
            int i = r3 / 1024;
            int r4 = r3 % 1024;
            int kb = r4 / 512;
            int r5 = r4 % 512;
            int lane = r5 / 8, j = r5 % 8;
            int c2 = mw * 16 + (lane & 15);
            int cl = kb * 32 + (lane >> 4) * 8 + j;
            const float* src = (br == 0) ? wb3 : (br == 1) ? wb5 : wb7;
            wTf[fi] = bf16r(src[((e * 64 + c2) * 64 + cl) * 3 + i]);
        }
    }

    // stage windowed frame
    for (int n = tid; n < NFFT; n += 128) {
        float a2 = (float)(2.0 * 3.14159265358979323846 / 256.0) * (float)n;
        float sn, cn;
        sincosf(a2, &sn, &cn);
        float win = 0.5f - 0.5f * cn;             // Hann
        int q = f * HOP + n - 128;
        int xi = q < 0 ? -q : (q >= LX ? (2 * LX - 2 - q) : q);  // reflect
        xw[n] = x[b * LX + xi] * win;
    }
    __syncthreads();

    const int k = tid;                            // bin 0..127
    float ang = (float)(2.0 * 3.14159265358979323846 / 256.0) * (float)k;
    float s1, c1;
    sincosf(ang, &s1, &c1);

    float A0 = 0.f, B0 = 0.f, A1 = 0.f, B1 = 0.f;
    float A2 = 0.f, B2 = 0.f, A3 = 0.f, B3 = 0.f;
    float c0 = 1.f, s0 = 0.f, cc1 = 1.f, ss1 = 0.f;
    float cc2 = 1.f, ss2 = 0.f, cc3 = 1.f, ss3 = 0.f;
    float rNe = 0.f, rNo = 0.f;

#pragma unroll 4
    for (int mq = 0; mq < 16; ++mq) {
        float4 v0 = *(const float4*)&xw[4 * mq];
        float4 v1 = *(const float4*)&xw[64 + 4 * mq];
        float4 v2 = *(const float4*)&xw[128 + 4 * mq];
        float4 v3 = *(const float4*)&xw[192 + 4 * mq];
        float e0[4] = {v0.x, v0.y, v0.z, v0.w};
        float e1[4] = {v1.x, v1.y, v1.z, v1.w};
        float e2[4] = {v2.x, v2.y, v2.z, v2.w};
        float e3[4] = {v3.x, v3.y, v3.z, v3.w};
#pragma unroll
        for (int mm = 0; mm < 4; ++mm) {
            float t;
            A0 = fmaf(e0[mm], c0, A0);  B0 = fmaf(e0[mm], s0, B0);
            A1 = fmaf(e1[mm], cc1, A1); B1 = fmaf(e1[mm], ss1, B1);
            A2 = fmaf(e2[mm], cc2, A2); B2 = fmaf(e2[mm], ss2, B2);
            A3 = fmaf(e3[mm], cc3, A3); B3 = fmaf(e3[mm], ss3, B3);
            if ((mm & 1) == 0) rNe += e0[mm] + e1[mm] + e2[mm] + e3[mm];
            else               rNo += e0[mm] + e1[mm] + e2[mm] + e3[mm];
            t = c0 * c1 - s0 * s1;   s0 = fmaf(c0, s1, s0 * c1);   c0 = t;
            t = cc1 * c1 - ss1 * s1; ss1 = fmaf(cc1, s1, ss1 * c1); cc1 = t;
            t = cc2 * c1 - ss2 * s1; ss2 = fmaf(cc2, s1, ss2 * c1); cc2 = t;
            t = cc3 * c1 - ss3 * s1; ss3 = fmaf(cc3, s1, ss3 * c1); cc3 = t;
        }
    }

    // recombine with chunk phases (j*k mod 4 -> cos/sin in {0,+-1})
    float re = A0, im = B0;
    float Aj[3] = {A1, A2, A3};
    float Bj[3] = {B1, B2, B3};
#pragma unroll
    for (int j = 1; j < 4; ++j) {
        int ph = (j * k) & 3;
        float cf = (ph == 0) ? 1.f : (ph == 2) ? -1.f : 0.f;
        float sf = (ph == 1) ? 1.f : (ph == 3) ? -1.f : 0.f;
        re += cf * Aj[j - 1] - sf * Bj[j - 1];
        im += sf * Aj[j - 1] + cf * Bj[j - 1];
    }

    float* prow = part + (b * NFG + f / 5) * PART_STRIDE;
    atomicAdd(&prow[k], sqrtf(re * re + im * im));
    if (tid == 0) atomicAdd(&prow[128], fabsf(rNe - rNo));
}

// ---------------- Gating MLP + top-2 softmax ----------------
__global__ __launch_bounds__(256) void gating_kernel(
    const float* __restrict__ part,
    const float* __restrict__ Wg1, const float* __restrict__ bg1,
    const float* __restrict__ Wg2, const float* __restrict__ bg2,
    const float* __restrict__ Wg3, const float* __restrict__ bg3,
    int* __restrict__ inds, float* __restrict__ wts) {
    __shared__ float pl[NBINS];
    __shared__ float h1[256];
    __shared__ float h2[128];
    __shared__ float lg[NE];
    const int b = blockIdx.x, tid = threadIdx.x;

    if (tid < NBINS) {
        float s = 0.f;
        for (int g = 0; g < NFG; ++g)
            s += part[(b * NFG + g) * PART_STRIDE + tid];
        pl[tid] = s * (1.0f / (float)NFRAMES);
    }
    __syncthreads();
    {
        float s = bg1[tid];
        for (int kk = 0; kk < NBINS; ++kk) s += pl[kk] * Wg1[kk * 256 + tid];
        h1[tid] = fmaxf(s, 0.f);
    }
    __syncthreads();
    if (tid < 128) {
        float s = bg2[tid];
        for (int kk = 0; kk < 256; ++kk) s += h1[kk] * Wg2[kk * 128 + tid];
        h2[tid] = fmaxf(s, 0.f);
    }
    __syncthreads();
    if (tid < NE) {
        float s = bg3[tid];
        for (int kk = 0; kk < 128; ++kk) s += h2[kk] * Wg3[kk * NE + tid];
        lg[tid] = s;
    }
    __syncthreads();
    if (tid == 0) {
        int i0 = 0;
        float v0 = lg[0];
        for (int i = 1; i < NE; ++i)
            if (lg[i] > v0) { v0 = lg[i]; i0 = i; }
        int i1 = -1;
        float v1 = -3.0e38f;
        for (int i = 0; i < NE; ++i) {
            if (i == i0) continue;
            if (lg[i] > v1) { v1 = lg[i]; i1 = i; }
        }
        float e1 = expf(v1 - v0);
        float w0 = 1.f / (1.f + e1);
        inds[b * 2 + 0] = i0;
        inds[b * 2 + 1] = i1;
        wts[b * 2 + 0] = w0;
        wts[b * 2 + 1] = e1 * w0;
    }
}

// ---------------- Expert path: fp32 conv1 -> bf16 MFMA conv2 ----------------
// (unchanged from R9: passed, absmax 2.4e-4)
#define UT 128
#define HPR 68           // shorts per hp row (64 + 4 pad)
#define HROWS 258

template <int KSZ>
__device__ __attribute__((always_inline)) void expert_body(
    const float* __restrict__ x,
    const float* __restrict__ wa, const float* __restrict__ ba,
    const float* __restrict__ bb, const unsigned short* __restrict__ wTfbr,
    const int* __restrict__ inds, const float* __restrict__ wts,
    float* __restrict__ out, int br, short* hp) {
    const int u0 = blockIdx.x * UT;
    const int b = blockIdx.z;
    const int tid = threadIdx.x;
    const int lane = tid & 63;
    const int quad = lane >> 4;
    const int l15 = lane & 15;
    const int wv = __builtin_amdgcn_readfirstlane(tid >> 6);
    const int mw = wv & 3;           // M-tile (c2 block of 16)
    const int nh = wv >> 2;          // N-half (4 N-tiles each)
    const int pad = KSZ >> 1;
    const int t0 = 2 * u0 - 1;
    const int x0 = 2 * t0 - pad;

    const float* xp = x + b * LX;

    float fin[4][4];
#pragma unroll
    for (int q = 0; q < 4; ++q)
#pragma unroll
        for (int r = 0; r < 4; ++r) fin[q][r] = 0.f;

#pragma unroll 1
    for (int slot = 0; slot < 2; ++slot) {
        const int e = __builtin_amdgcn_readfirstlane(inds[b * 2 + slot]);
        const float wj = wts[b * 2 + slot];

        // first-conv weights for this lane's channel (cl = lane)
        float wr[KSZ];
#pragma unroll
        for (int i = 0; i < KSZ; ++i) wr[i] = wa[(e * NCH + lane) * KSZ + i];
        const float bv = ba[e * NCH + lane];

        __syncthreads();   // protect hp from previous slot's phase C readers

        // ---- phase A: h rows tl = 0..257 ----
#pragma unroll 1
        for (int it = 0; it < 9; ++it) {
            int tb = wv + 8 * it;            // wave-uniform t-block (4 rows)
            if (tb > 64) break;
            int base = x0 + 8 * tb;          // wave-uniform x base
            float xr[16];
            if (base >= 0 && base + 15 < LX) {
#pragma unroll
                for (int ii = 0; ii < 16; ++ii) xr[ii] = xp[base + ii];
            } else {
#pragma unroll
                for (int ii = 0; ii < 16; ++ii) {
                    int xi = base + ii;
                    xr[ii] = (xi >= 0 && xi < LX) ? xp[xi] : 0.f;
                }
            }
#pragma unroll
            for (int m = 0; m < 4; ++m) {
                int tl = 4 * tb + m;
                if (tl > 257) continue;
                int t = t0 + tl;
                float s = bv;
#pragma unroll
                for (int i = 0; i < KSZ; ++i) s += wr[i] * xr[2 * m + i];
                float h = (t >= 0 && t < LH) ? fmaxf(s, 0.f) : 0.f;
                hp[tl * HPR + lane] = (short)bf16r(h);
            }
        }
        __syncthreads();

        // ---- phase C: MFMA GEMM ----
        float br4[4];
#pragma unroll
        for (int r = 0; r < 4; ++r)
            br4[r] = bb[e * NCH + mw * 16 + quad * 4 + r];

        short8 af[3][2];
        {
            const unsigned short* wbase =
                wTfbr + e * 12288 + mw * 3072 + lane * 8;
#pragma unroll
            for (int i = 0; i < 3; ++i)
#pragma unroll
                for (int kb = 0; kb < 2; ++kb)
                    af[i][kb] = *(const short8*)&wbase[i * 1024 + kb * 512];
        }

#pragma unroll 1
        for (int q = 0; q < 4; ++q) {
            int nt = nh * 4 + q;
            int nb = nt * 16 + l15;          // local u (B-layout n = lane&15)
            floatx4 acc = {br4[0], br4[1], br4[2], br4[3]};
#pragma unroll
            for (int i = 0; i < 3; ++i) {
                int tl = 2 * nb + i;         // B row
#pragma unroll
                for (int kb = 0; kb < 2; ++kb) {
                    int sb = tl * HPR + kb * 32 + quad * 8;
                    union { short8 v; unsigned long long q2[2]; } B;
                    B.q2[0] = *(const unsigned long long*)&hp[sb];
                    B.q2[1] = *(const unsigned long long*)&hp[sb + 4];
                    acc = __builtin_amdgcn_mfma_f32_16x16x32_bf16(
                        af[i][kb], B.v, acc, 0, 0, 0);
                }
            }
#pragma unroll
            for (int r = 0; r < 4; ++r)
                fin[q][r] += wj * fmaxf(acc[r], 0.f);
        }
    }

#pragma unroll
    for (int q = 0; q < 4; ++q) {
        int u = u0 + (nh * 4 + q) * 16 + l15;
#pragma unroll
        for (int r = 0; r < 4; ++r) {
            int c2 = mw * 16 + quad * 4 + r;
            out[(long)(b * 192 + br * 64 + c2) * LY + u] = fin[q][r];
        }
    }
}

__global__ __launch_bounds__(512, 2) void expert_kernel(
    const float* __restrict__ x,
    const float* __restrict__ wa3, const float* __restrict__ ba3,
    const float* __restrict__ bb3,
    const float* __restrict__ wa5, const float* __restrict__ ba5,
    const float* __restrict__ bb5,
    const float* __restrict__ wa7, const float* __restrict__ ba7,
    const float* __restrict__ bb7,
    const unsigned short* __restrict__ wTf,
    const int* __restrict__ inds, const float* __restrict__ wts,
    float* __restrict__ out) {
    __shared__ short hp[HROWS * HPR];      // 35.1 KB

    const int br = blockIdx.y;
    if (br == 0)
        expert_body<3>(x, wa3, ba3, bb3, wTf, inds, wts, out, 0, hp);
    else if (br == 1)
        expert_body<5>(x, wa5, ba5, bb5, wTf + WTF_PER, inds, wts, out, 1, hp);
    else
        expert_body<7>(x, wa7, ba7, bb7, wTf + 2 * WTF_PER, inds, wts, out, 2, hp);
}

extern "C" void kernel_launch(void* const* d_in, const int* in_sizes, int n_in,
                              void* d_out, int out_size, void* d_ws, size_t ws_size,
                              hipStream_t stream) {
    const float* x   = (const float*)d_in[0];
    const float* Wg1 = (const float*)d_in[1];
    const float* bg1 = (const float*)d_in[2];
    const float* Wg2 = (const float*)d_in[3];
    const float* bg2 = (const float*)d_in[4];
    const float* Wg3 = (const float*)d_in[5];
    const float* bg3 = (const float*)d_in[6];
    const float* wa3 = (const float*)d_in[7];
    const float* ba3 = (const float*)d_in[8];
    const float* wb3 = (const float*)d_in[9];
    const float* bb3 = (const float*)d_in[10];
    const float* wa5 = (const float*)d_in[11];
    const float* ba5 = (const float*)d_in[12];
    const float* wb5 = (const float*)d_in[13];
    const float* bb5 = (const float*)d_in[14];
    const float* wa7 = (const float*)d_in[15];
    const float* ba7 = (const float*)d_in[16];
    const float* wb7 = (const float*)d_in[17];
    const float* bb7 = (const float*)d_in[18];

    float* part = (float*)d_ws;
    unsigned short* wTf = (unsigned short*)((char*)d_ws + WTF_OFF);
    int* inds = (int*)((char*)d_ws + IW_OFF);
    float* wts = (float*)((char*)d_ws + IW_OFF + 512);

    hipMemsetAsync(d_ws, 0, PART_ZERO, stream);
    stft_kernel<<<dim3(NFRAMES, NB), 128, 0, stream>>>(x, wb3, wb5, wb7, wTf,
                                                       part);
    gating_kernel<<<NB, 256, 0, stream>>>(part, Wg1, bg1, Wg2, bg2, Wg3, bg3,
                                          inds, wts);
    expert_kernel<<<dim3(LY / UT, NBR, NB), 512, 0, stream>>>(
        x, wa3, ba3, bb3, wa5, ba5, bb5, wa7, ba7, bb7, wTf,
        inds, wts, (float*)d_out);
}